// Round 1
// baseline (518.810 us; speedup 1.0000x reference)
//
#include <hip/hip_runtime.h>
#include <hip/hip_bf16.h>

#define B_ 64
#define N_ 8192
#define C_ 64
#define PAD 68   // 64 + 4: keeps float4 (16B) alignment, breaks power-of-2 bank strides

// ---- helpers -------------------------------------------------------------
__device__ inline void mac4(float4& acc, const float4 a,
                            const float4 w0, const float4 w1,
                            const float4 w2, const float4 w3) {
  acc.x = fmaf(a.x, w0.x, fmaf(a.y, w1.x, fmaf(a.z, w2.x, fmaf(a.w, w3.x, acc.x))));
  acc.y = fmaf(a.x, w0.y, fmaf(a.y, w1.y, fmaf(a.z, w2.y, fmaf(a.w, w3.y, acc.y))));
  acc.z = fmaf(a.x, w0.z, fmaf(a.y, w1.z, fmaf(a.z, w2.z, fmaf(a.w, w3.z, acc.z))));
  acc.w = fmaf(a.x, w0.w, fmaf(a.y, w1.w, fmaf(a.z, w2.w, fmaf(a.w, w3.w, acc.w))));
}
__device__ inline void macs(float4& acc, const float a, const float4 w) {
  acc.x = fmaf(a, w.x, acc.x);
  acc.y = fmaf(a, w.y, acc.y);
  acc.z = fmaf(a, w.z, acc.z);
  acc.w = fmaf(a, w.w, acc.w);
}

// ---- k0: zero the stats accumulators ------------------------------------
__global__ void k0_init(float* __restrict__ stats) {
  int i = blockIdx.x * 256 + threadIdx.x;
  if (i < 1024) stats[i] = 0.f;
}

// ---- k1: per-point attention chain, one block per n ----------------------
__global__ __launch_bounds__(256, 2)
void k1_attn(const float* __restrict__ x, const float* __restrict__ y,
             const float* __restrict__ W_l, const float* __restrict__ b_l,
             const float* __restrict__ W_r, const float* __restrict__ b_r,
             const float* __restrict__ W_qk, const float* __restrict__ W_v,
             const float* __restrict__ b_v, const float* __restrict__ W_t,
             const float* __restrict__ b_t,
             __hip_bfloat16* __restrict__ tg, float* __restrict__ stats)
{
  // LDS budget: 4*64*68*4 + 3*4096 = 81920 B exactly -> 2 blocks/CU
  __shared__ float Xs[64 * PAD];   // X, then Z = X - yr
  __shared__ float Bs[64 * PAD];   // Y, then energy/attn
  __shared__ float Vs[64 * PAD];   // yv, then t
  __shared__ float Wb[64 * PAD];   // W_v^T, then W_t^T
  __shared__ float xqs[1024];      // xq [64][16]; later red1/red2 scratch
  __shared__ float Wqs[1024];      // W_qk^T [64 rows c][16 d]; later csv
  __shared__ float ykT[16 * 64];   // yk^T [16 d][64 e]

  float* const red1 = xqs;         // 256 floats (xq dead by then)
  float* const red2 = xqs + 256;   // 256 floats
  float* const csv  = Wqs;         // 64 floats (Wqs dead by then)

  const int n   = blockIdx.x;
  const int tid = threadIdx.x;
  const int tx  = tid & 15;        // output-col tile
  const int ty  = tid >> 4;        // output-row tile
  const int c0  = tx * 4;
  const int b0  = ty * 4;

  // ---- stage W_v^T and W_qk^T ----
  for (int i = tid; i < 4096; i += 256) {
    int r = i >> 6, c = i & 63;            // W_v[r][c] (r = out ch, c = in ch)
    Wb[c * PAD + r] = W_v[i];              // Wb[k][d]
  }
  for (int i = tid; i < 1024; i += 256) {
    int d = i >> 6, c = i & 63;            // W_qk[d][c]
    Wqs[c * 16 + d] = W_qk[i];             // Wqs[c][d]
  }

  // ---- X = x@W_l + b_l ; Y = y@W_r + b_r  (per wave: b uniform, c = lane) ----
  for (int i = tid; i < 4096; i += 256) {
    int b = i >> 6, c = i & 63;
    const float* xp = x + ((size_t)b * N_ + n) * 10;
    const float* yp = y + ((size_t)b * N_ + n) * 13;
    float ax = b_l[c];
#pragma unroll
    for (int k = 0; k < 10; ++k) ax = fmaf(xp[k], W_l[k * 64 + c], ax);
    float ay = b_r[c];
#pragma unroll
    for (int k = 0; k < 13; ++k) ay = fmaf(yp[k], W_r[k * 64 + c], ay);
    Xs[b * PAD + c] = ax;
    Bs[b * PAD + c] = ay;
  }
  __syncthreads();

  // ---- xq[b][d], yk[b][d] (thread: b = tid>>2, 4 d's) ----
  {
    const int dq = tid & 3, b = tid >> 2;
    float4 xa = {0.f, 0.f, 0.f, 0.f};
    float4 ya = {0.f, 0.f, 0.f, 0.f};
    for (int c = 0; c < 64; ++c) {
      const float a1 = Xs[b * PAD + c];
      const float a2 = Bs[b * PAD + c];
      const float4 w = *(const float4*)&Wqs[c * 16 + dq * 4];
      macs(xa, a1, w);
      macs(ya, a2, w);
    }
    *(float4*)&xqs[b * 16 + dq * 4] = xa;
    ykT[(dq * 4 + 0) * 64 + b] = ya.x;     // store yk transposed: ykT[d][e]
    ykT[(dq * 4 + 1) * 64 + b] = ya.y;
    ykT[(dq * 4 + 2) * 64 + b] = ya.z;
    ykT[(dq * 4 + 3) * 64 + b] = ya.w;
  }

  // ---- yv[e][c] = Y @ W_v^T + b_v (4x4 register tile, float4 LDS reads) ----
  {
    const float4 bv = *(const float4*)&b_v[c0];
    float4 a0c = bv, a1c = bv, a2c = bv, a3c = bv;
    for (int k = 0; k < 64; k += 4) {
      const float4 w0 = *(const float4*)&Wb[(k + 0) * PAD + c0];
      const float4 w1 = *(const float4*)&Wb[(k + 1) * PAD + c0];
      const float4 w2 = *(const float4*)&Wb[(k + 2) * PAD + c0];
      const float4 w3 = *(const float4*)&Wb[(k + 3) * PAD + c0];
      const float4 q0 = *(const float4*)&Bs[(b0 + 0) * PAD + k];
      const float4 q1 = *(const float4*)&Bs[(b0 + 1) * PAD + k];
      const float4 q2 = *(const float4*)&Bs[(b0 + 2) * PAD + k];
      const float4 q3 = *(const float4*)&Bs[(b0 + 3) * PAD + k];
      mac4(a0c, q0, w0, w1, w2, w3);
      mac4(a1c, q1, w0, w1, w2, w3);
      mac4(a2c, q2, w0, w1, w2, w3);
      mac4(a3c, q3, w0, w1, w2, w3);
    }
    *(float4*)&Vs[(b0 + 0) * PAD + c0] = a0c;
    *(float4*)&Vs[(b0 + 1) * PAD + c0] = a1c;
    *(float4*)&Vs[(b0 + 2) * PAD + c0] = a2c;
    *(float4*)&Vs[(b0 + 3) * PAD + c0] = a3c;
  }
  __syncthreads();   // Y consumers done; xqs/ykT/Vs visible

  // ---- stage W_t^T into Wb (W_v^T dead) ----
  for (int i = tid; i < 4096; i += 256) {
    int r = i >> 6, c = i & 63;            // W_t[r][c]
    Wb[c * PAD + r] = W_t[i];              // Wb[c_in][d_out]
  }

  // ---- energy[b][e] = xq[b][:] . yk[e][:]  -> into Bs (Y dead) ----
  {
    float4 e0 = {0,0,0,0}, e1 = {0,0,0,0}, e2 = {0,0,0,0}, e3 = {0,0,0,0};
    for (int d = 0; d < 16; ++d) {
      const float4 w = *(const float4*)&ykT[d * 64 + c0];
      macs(e0, xqs[(b0 + 0) * 16 + d], w);
      macs(e1, xqs[(b0 + 1) * 16 + d], w);
      macs(e2, xqs[(b0 + 2) * 16 + d], w);
      macs(e3, xqs[(b0 + 3) * 16 + d], w);
    }
    *(float4*)&Bs[(b0 + 0) * PAD + c0] = e0;
    *(float4*)&Bs[(b0 + 1) * PAD + c0] = e1;
    *(float4*)&Bs[(b0 + 2) * PAD + c0] = e2;
    *(float4*)&Bs[(b0 + 3) * PAD + c0] = e3;
  }
  __syncthreads();

  // ---- softmax over e, 4 threads per row (shfl within lane-quad) ----
  {
    const int brow = tid >> 2, q = tid & 3;
    float* rp = &Bs[brow * PAD + q * 16];
    float m = -1e30f;
#pragma unroll
    for (int j = 0; j < 16; ++j) m = fmaxf(m, rp[j]);
    m = fmaxf(m, __shfl_xor(m, 1));
    m = fmaxf(m, __shfl_xor(m, 2));
    float s = 0.f;
#pragma unroll
    for (int j = 0; j < 16; ++j) { float v = __expf(rp[j] - m); rp[j] = v; s += v; }
    s += __shfl_xor(s, 1);
    s += __shfl_xor(s, 2);
    const float inv = 1.0f / s;
#pragma unroll
    for (int j = 0; j < 16; ++j) rp[j] *= inv;
  }
  __syncthreads();

  // ---- column sums over b (L1 renorm factors) ----
  {
    const int q = tid >> 6, e = tid & 63;
    float s = 0.f;
    for (int b = q * 16; b < q * 16 + 16; ++b) s += Bs[b * PAD + e];
    red1[tid] = s;
  }
  __syncthreads();
  if (tid < 64)
    csv[tid] = 1.0f / (1e-9f + red1[tid] + red1[64 + tid] + red1[128 + tid] + red1[192 + tid]);
  __syncthreads();

  // ---- yr = (attn * csv) @ yv ; Z = X - yr (in place in Xs) ----
  {
    float4 r0 = {0,0,0,0}, r1 = {0,0,0,0}, r2 = {0,0,0,0}, r3 = {0,0,0,0};
    for (int e = 0; e < 64; e += 4) {
      const float4 ce = *(const float4*)&csv[e];
      float4 w0 = *(const float4*)&Vs[(e + 0) * PAD + c0];
      float4 w1 = *(const float4*)&Vs[(e + 1) * PAD + c0];
      float4 w2 = *(const float4*)&Vs[(e + 2) * PAD + c0];
      float4 w3 = *(const float4*)&Vs[(e + 3) * PAD + c0];
      w0.x *= ce.x; w0.y *= ce.x; w0.z *= ce.x; w0.w *= ce.x;
      w1.x *= ce.y; w1.y *= ce.y; w1.z *= ce.y; w1.w *= ce.y;
      w2.x *= ce.z; w2.y *= ce.z; w2.z *= ce.z; w2.w *= ce.z;
      w3.x *= ce.w; w3.y *= ce.w; w3.z *= ce.w; w3.w *= ce.w;
      const float4 a0 = *(const float4*)&Bs[(b0 + 0) * PAD + e];
      const float4 a1 = *(const float4*)&Bs[(b0 + 1) * PAD + e];
      const float4 a2 = *(const float4*)&Bs[(b0 + 2) * PAD + e];
      const float4 a3 = *(const float4*)&Bs[(b0 + 3) * PAD + e];
      mac4(r0, a0, w0, w1, w2, w3);
      mac4(r1, a1, w0, w1, w2, w3);
      mac4(r2, a2, w0, w1, w2, w3);
      mac4(r3, a3, w0, w1, w2, w3);
    }
#pragma unroll
    for (int j = 0; j < 4; ++j) {
      float4 xv = *(float4*)&Xs[(b0 + j) * PAD + c0];
      const float4 rr = (j == 0) ? r0 : (j == 1) ? r1 : (j == 2) ? r2 : r3;
      xv.x -= rr.x; xv.y -= rr.y; xv.z -= rr.z; xv.w -= rr.w;
      *(float4*)&Xs[(b0 + j) * PAD + c0] = xv;
    }
  }
  __syncthreads();

  // ---- t = Z @ W_t^T + b_t -> into Vs (yv dead) ----
  {
    const float4 bt = *(const float4*)&b_t[c0];
    float4 t0 = bt, t1 = bt, t2 = bt, t3 = bt;
    for (int k = 0; k < 64; k += 4) {
      const float4 w0 = *(const float4*)&Wb[(k + 0) * PAD + c0];
      const float4 w1 = *(const float4*)&Wb[(k + 1) * PAD + c0];
      const float4 w2 = *(const float4*)&Wb[(k + 2) * PAD + c0];
      const float4 w3 = *(const float4*)&Wb[(k + 3) * PAD + c0];
      const float4 a0 = *(const float4*)&Xs[(b0 + 0) * PAD + k];
      const float4 a1 = *(const float4*)&Xs[(b0 + 1) * PAD + k];
      const float4 a2 = *(const float4*)&Xs[(b0 + 2) * PAD + k];
      const float4 a3 = *(const float4*)&Xs[(b0 + 3) * PAD + k];
      mac4(t0, a0, w0, w1, w2, w3);
      mac4(t1, a1, w0, w1, w2, w3);
      mac4(t2, a2, w0, w1, w2, w3);
      mac4(t3, a3, w0, w1, w2, w3);
    }
    *(float4*)&Vs[(b0 + 0) * PAD + c0] = t0;
    *(float4*)&Vs[(b0 + 1) * PAD + c0] = t1;
    *(float4*)&Vs[(b0 + 2) * PAD + c0] = t2;
    *(float4*)&Vs[(b0 + 3) * PAD + c0] = t3;
  }
  __syncthreads();

  // ---- per-channel partial stats + bf16 store of t ----
  {
    const int q = tid >> 6, c = tid & 63;
    float s = 0.f, ss = 0.f;
    for (int b = q * 16; b < q * 16 + 16; ++b) {
      const float v = Vs[b * PAD + c];
      s += v; ss = fmaf(v, v, ss);
    }
    red1[tid] = s;
    red2[tid] = ss;
  }
  __hip_bfloat16* tp = tg + (size_t)n * 4096;
  for (int i = tid; i < 4096; i += 256)
    tp[i] = __float2bfloat16(Vs[(i >> 6) * PAD + (i & 63)]);
  __syncthreads();
  if (tid < 64) {
    const float s  = red1[tid] + red1[64 + tid] + red1[128 + tid] + red1[192 + tid];
    const float ss = red2[tid] + red2[64 + tid] + red2[128 + tid] + red2[192 + tid];
    float* st = stats + (n & 7) * 128;   // 8 copies to spread atomic contention
    atomicAdd(&st[tid], s);
    atomicAdd(&st[64 + tid], ss);
  }
}

// ---- k2: finalize BN stats ----------------------------------------------
__global__ void k2_stats(const float* __restrict__ stats, float* __restrict__ meanr) {
  const int c = threadIdx.x;
  if (c < 64) {
    float s = 0.f, ss = 0.f;
    for (int r = 0; r < 8; ++r) { s += stats[r * 128 + c]; ss += stats[r * 128 + 64 + c]; }
    const float inv = 1.0f / (float)(B_ * N_);
    const float mu = s * inv;
    const float var = fmaf(ss, inv, -mu * mu);
    meanr[c] = mu;
    meanr[64 + c] = rsqrtf(var + 1e-5f);
  }
}

// ---- k3: recompute X, BN+ReLU+residual, partial max over n ---------------
__global__ __launch_bounds__(256)
void k3_max(const float* __restrict__ x, const float* __restrict__ W_l,
            const float* __restrict__ b_l, const float* __restrict__ gamma,
            const float* __restrict__ beta, const __hip_bfloat16* __restrict__ tg,
            const float* __restrict__ meanr, float* __restrict__ pmax)
{
  const int b = blockIdx.x >> 3;      // 0..63
  const int chunk = blockIdx.x & 7;   // 0..7 (1024 n's each)
  const int c = threadIdx.x & 63;
  const int sub = threadIdx.x >> 6;   // 0..3
  float wl[10];
#pragma unroll
  for (int k = 0; k < 10; ++k) wl[k] = W_l[k * 64 + c];
  const float bl = b_l[c];
  const float g = gamma[c], be = beta[c];
  const float mu = meanr[c], rs = meanr[64 + c];
  float m = -1e30f;
  const int nbase = chunk * 1024 + sub;
  for (int j = 0; j < 256; ++j) {
    const int n = nbase + j * 4;
    const float* xp = x + ((size_t)b * N_ + n) * 10;
    float X = bl;
#pragma unroll
    for (int k = 0; k < 10; ++k) X = fmaf(xp[k], wl[k], X);
    const float t = __bfloat162float(tg[(size_t)n * 4096 + b * 64 + c]);
    const float tn = fmaf(g * (t - mu), rs, be);
    m = fmaxf(m, X + fmaxf(tn, 0.f));
  }
  __shared__ float sm[4][64];
  sm[sub][c] = m;
  __syncthreads();
  if (threadIdx.x < 64) {
    const float r = fmaxf(fmaxf(sm[0][c], sm[1][c]), fmaxf(sm[2][c], sm[3][c]));
    pmax[(size_t)blockIdx.x * 64 + c] = r;
  }
}

// ---- k4: final max over chunks -------------------------------------------
__global__ void k4_final(const float* __restrict__ pmax, float* __restrict__ out) {
  const int b = blockIdx.x, c = threadIdx.x;
  float m = -1e30f;
  for (int ch = 0; ch < 8; ++ch) m = fmaxf(m, pmax[((size_t)b * 8 + ch) * 64 + c]);
  out[b * 64 + c] = m;
}

// ---- launcher -------------------------------------------------------------
extern "C" void kernel_launch(void* const* d_in, const int* in_sizes, int n_in,
                              void* d_out, int out_size, void* d_ws, size_t ws_size,
                              hipStream_t stream) {
  const float* x     = (const float*)d_in[0];
  const float* y     = (const float*)d_in[1];
  const float* W_l   = (const float*)d_in[2];
  const float* b_l   = (const float*)d_in[3];
  const float* W_r   = (const float*)d_in[4];
  const float* b_r   = (const float*)d_in[5];
  const float* W_qk  = (const float*)d_in[6];
  const float* W_v   = (const float*)d_in[7];
  const float* b_v   = (const float*)d_in[8];
  const float* W_t   = (const float*)d_in[9];
  const float* b_t   = (const float*)d_in[10];
  const float* gamma = (const float*)d_in[11];
  const float* beta  = (const float*)d_in[12];
  float* out = (float*)d_out;

  char* ws = (char*)d_ws;
  __hip_bfloat16* tg = (__hip_bfloat16*)ws;                  // [N][B][C] bf16, 64 MB
  float* stats = (float*)(ws + (size_t)N_ * B_ * C_ * 2);    // 8 copies x 128
  float* meanr = stats + 1024;                               // mean[64] + rsig[64]
  float* pmax  = meanr + 128;                                // [512][64]

  hipLaunchKernelGGL(k0_init, dim3(4), dim3(256), 0, stream, stats);
  hipLaunchKernelGGL(k1_attn, dim3(N_), dim3(256), 0, stream,
                     x, y, W_l, b_l, W_r, b_r, W_qk, W_v, b_v, W_t, b_t, tg, stats);
  hipLaunchKernelGGL(k2_stats, dim3(1), dim3(64), 0, stream, stats, meanr);
  hipLaunchKernelGGL(k3_max, dim3(512), dim3(256), 0, stream,
                     x, W_l, b_l, gamma, beta, tg, meanr, pmax);
  hipLaunchKernelGGL(k4_final, dim3(64), dim3(64), 0, stream, pmax, out);
}

// Round 2
// 325.337 us; speedup vs baseline: 1.5947x; 1.5947x over previous
//
#include <hip/hip_runtime.h>
#include <hip/hip_bf16.h>

#define B_ 64
#define N_ 8192
#define C_ 64

using short8 = __attribute__((ext_vector_type(8))) short;  // 8 bf16 (4 VGPRs)
using f32x4  = __attribute__((ext_vector_type(4))) float;

#define MFMA16(a, b, c) __builtin_amdgcn_mfma_f32_16x16x32_bf16((a), (b), (c), 0, 0, 0)

__device__ inline unsigned short f2bf(float f) {
  union { float f; unsigned int u; } v; v.f = f;
  unsigned int r = v.u + 0x7FFFu + ((v.u >> 16) & 1u);   // RNE
  return (unsigned short)(r >> 16);
}
__device__ inline float bf2f(unsigned short s) {
  union { unsigned int u; float f; } v; v.u = ((unsigned int)s) << 16;
  return v.f;
}

// ---- k0: zero the stats accumulators ------------------------------------
__global__ void k0_init(float* __restrict__ stats) {
  int i = blockIdx.x * 256 + threadIdx.x;
  if (i < 1024) stats[i] = 0.f;
}

// ---- k1: per-point attention chain via bf16 MFMA, one block per n --------
// LDS: 24704 shorts (49408 B) + 576 f32 (2304 B) = 51712 B -> 3 blocks/CU
__global__ __launch_bounds__(256, 3)
void k1_attn(const float* __restrict__ x, const float* __restrict__ y,
             const float* __restrict__ W_l, const float* __restrict__ b_l,
             const float* __restrict__ W_r, const float* __restrict__ b_r,
             const float* __restrict__ W_qk, const float* __restrict__ W_v,
             const float* __restrict__ b_v, const float* __restrict__ W_t,
             const float* __restrict__ b_t,
             __hip_bfloat16* __restrict__ tg, float* __restrict__ stats)
{
  __shared__ __align__(16) short lds[24704];
  __shared__ float scr[576];                  // [0:256) colsum/S, [256:512) SS, [512:576) csv
  short* const Xs   = lds;                    // [64][72] bf16  X
  short* const Ys   = lds + 4608;             // [64][72]       Y   (later yvT[c][e])
  short* const Wv   = lds + 2 * 4608;         // [64][72]       W_v (later Zs)
  short* const Wt   = lds + 3 * 4608;         // [64][72]       W_t
  short* const Wq   = lds + 4 * 4608;         // [16][72]       W_qk
  short* const xqA  = Wq + 1152;              // [64][40] xq (k 16..31 zero)
  short* const ykB  = xqA + 2560;             // [64][40] yk
  short* const yvT  = Ys;                     // overlay after S2
  short* const attnA= Wq;                     // [64][72] overlay after S4 (4608 <= 1152+2560+2560)
  short* const Zs   = Wv;                     // overlay after S5
  float* const csv  = scr + 512;

  const int n    = blockIdx.x;
  const int tid  = threadIdx.x;
  const int w    = tid >> 6;     // wave 0..3
  const int lane = tid & 63;
  const int l15  = lane & 15;
  const int q    = lane >> 4;    // 0..3
  const int r0   = w * 16;       // this wave's 16 output rows

  // ---- zero xqA+ykB (so k=16..31 pad is 0) ----
  {
    int* zp = (int*)xqA;
    for (int i = tid; i < 2560; i += 256) zp[i] = 0;
  }
  // ---- stage weights as bf16 (row d, col c: B-operand-ready) ----
  for (int i = tid; i < 4096; i += 256) {
    int d = i >> 6, c = i & 63;
    Wv[d * 72 + c] = (short)f2bf(W_v[i]);
    Wt[d * 72 + c] = (short)f2bf(W_t[i]);
  }
  for (int i = tid; i < 1024; i += 256) {
    int d = i >> 6, c = i & 63;
    Wq[d * 72 + c] = (short)f2bf(W_qk[i]);
  }
  // ---- X = x@W_l + b_l ; Y = y@W_r + b_r  (K=10/13, VALU) ----
  for (int i = tid; i < 4096; i += 256) {
    int b = i >> 6, c = i & 63;
    const float* xp = x + ((size_t)b * N_ + n) * 10;
    const float* yp = y + ((size_t)b * N_ + n) * 13;
    float ax = b_l[c];
#pragma unroll
    for (int k = 0; k < 10; ++k) ax = fmaf(xp[k], W_l[k * 64 + c], ax);
    float ay = b_r[c];
#pragma unroll
    for (int k = 0; k < 13; ++k) ay = fmaf(yp[k], W_r[k * 64 + c], ay);
    Xs[b * 72 + c] = (short)f2bf(ax);
    Ys[b * 72 + c] = (short)f2bf(ay);
  }
  __syncthreads();  // S1

  // ---- xq = X Wqk^T, yk = Y Wqk^T, yv = Y Wv^T + b_v ----
  const short8 aX0 = *(const short8*)&Xs[(r0 + l15) * 72 + q * 8];
  const short8 aX1 = *(const short8*)&Xs[(r0 + l15) * 72 + 32 + q * 8];
  const short8 aY0 = *(const short8*)&Ys[(r0 + l15) * 72 + q * 8];
  const short8 aY1 = *(const short8*)&Ys[(r0 + l15) * 72 + 32 + q * 8];
  const short8 bQ0 = *(const short8*)&Wq[l15 * 72 + q * 8];
  const short8 bQ1 = *(const short8*)&Wq[l15 * 72 + 32 + q * 8];
  f32x4 xq = {0.f, 0.f, 0.f, 0.f}, yk = {0.f, 0.f, 0.f, 0.f};
  xq = MFMA16(aX0, bQ0, xq);  xq = MFMA16(aX1, bQ1, xq);
  yk = MFMA16(aY0, bQ0, yk);  yk = MFMA16(aY1, bQ1, yk);
  f32x4 yv[4];
#pragma unroll
  for (int f = 0; f < 4; ++f) {
    const float bv = b_v[f * 16 + l15];
    yv[f] = (f32x4){bv, bv, bv, bv};
    const short8 b0 = *(const short8*)&Wv[(f * 16 + l15) * 72 + q * 8];
    const short8 b1 = *(const short8*)&Wv[(f * 16 + l15) * 72 + 32 + q * 8];
    yv[f] = MFMA16(aY0, b0, yv[f]);
    yv[f] = MFMA16(aY1, b1, yv[f]);
  }
  // C-layout scatter: row = r0+q*4+j, col = l15
#pragma unroll
  for (int j = 0; j < 4; ++j) {
    xqA[(r0 + q * 4 + j) * 40 + l15] = (short)f2bf(xq[j]);
    ykB[(r0 + q * 4 + j) * 40 + l15] = (short)f2bf(yk[j]);
  }
  __syncthreads();  // S2: xqA/ykB visible; Ys fully consumed

  // yvT[c][e] <- yv C-frags (col c = f*16+l15, row e = r0+q*4+j)
#pragma unroll
  for (int f = 0; f < 4; ++f)
#pragma unroll
    for (int j = 0; j < 4; ++j)
      yvT[(f * 16 + l15) * 72 + (r0 + q * 4 + j)] = (short)f2bf(yv[f][j]);

  // ---- E = xq yk^T (K=16 zero-padded to 32) ----
  const short8 aq = *(const short8*)&xqA[(r0 + l15) * 40 + q * 8];
  f32x4 E[4];
#pragma unroll
  for (int f = 0; f < 4; ++f) {
    const short8 bk = *(const short8*)&ykB[(f * 16 + l15) * 40 + q * 8];
    E[f] = (f32x4){0.f, 0.f, 0.f, 0.f};
    E[f] = MFMA16(aq, bk, E[f]);
  }

  // ---- row softmax in registers (row = r0+q*4+j spans (f,l15)) ----
  float inv_r[4];
#pragma unroll
  for (int j = 0; j < 4; ++j) {
    float m = fmaxf(fmaxf(E[0][j], E[1][j]), fmaxf(E[2][j], E[3][j]));
    m = fmaxf(m, __shfl_xor(m, 1));
    m = fmaxf(m, __shfl_xor(m, 2));
    m = fmaxf(m, __shfl_xor(m, 4));
    m = fmaxf(m, __shfl_xor(m, 8));
    float s = 0.f;
#pragma unroll
    for (int f = 0; f < 4; ++f) { E[f][j] = __expf(E[f][j] - m); s += E[f][j]; }
    s += __shfl_xor(s, 1);
    s += __shfl_xor(s, 2);
    s += __shfl_xor(s, 4);
    s += __shfl_xor(s, 8);
    inv_r[j] = 1.0f / s;
  }
  // ---- column sums (over rows) of attn = p*inv_r ----
#pragma unroll
  for (int f = 0; f < 4; ++f) {
    float cs = E[f][0] * inv_r[0] + E[f][1] * inv_r[1] + E[f][2] * inv_r[2] + E[f][3] * inv_r[3];
    cs += __shfl_xor(cs, 16);
    cs += __shfl_xor(cs, 32);
    if (lane < 16) scr[w * 64 + f * 16 + l15] = cs;
  }
  __syncthreads();  // S3: colsum partials visible; also fences yvT writes & E reads
  if (tid < 64)
    csv[tid] = 1.0f / (1e-9f + scr[tid] + scr[64 + tid] + scr[128 + tid] + scr[192 + tid]);
  __syncthreads();  // S4
  // ---- write attnA[b][e] bf16 (overlays Wq/xqA/ykB) ----
#pragma unroll
  for (int f = 0; f < 4; ++f) {
    const float a = csv[f * 16 + l15];
#pragma unroll
    for (int j = 0; j < 4; ++j)
      attnA[(r0 + q * 4 + j) * 72 + f * 16 + l15] = (short)f2bf(E[f][j] * inv_r[j] * a);
  }
  __syncthreads();  // S5

  // ---- yr = attn yv ; Z = X - yr ----
  const short8 aA0 = *(const short8*)&attnA[(r0 + l15) * 72 + q * 8];
  const short8 aA1 = *(const short8*)&attnA[(r0 + l15) * 72 + 32 + q * 8];
#pragma unroll
  for (int f = 0; f < 4; ++f) {
    const short8 b0 = *(const short8*)&yvT[(f * 16 + l15) * 72 + q * 8];
    const short8 b1 = *(const short8*)&yvT[(f * 16 + l15) * 72 + 32 + q * 8];
    f32x4 yr = {0.f, 0.f, 0.f, 0.f};
    yr = MFMA16(aA0, b0, yr);
    yr = MFMA16(aA1, b1, yr);
#pragma unroll
    for (int j = 0; j < 4; ++j) {
      const int row = r0 + q * 4 + j, col = f * 16 + l15;
      const float xv = bf2f((unsigned short)Xs[row * 72 + col]);
      Zs[row * 72 + col] = (short)f2bf(xv - yr[j]);   // Zs overlays Wv (dead)
    }
  }
  __syncthreads();  // S6

  // ---- t = Z W_t^T + b_t ----
  const short8 aZ0 = *(const short8*)&Zs[(r0 + l15) * 72 + q * 8];
  const short8 aZ1 = *(const short8*)&Zs[(r0 + l15) * 72 + 32 + q * 8];
  f32x4 t[4];
#pragma unroll
  for (int f = 0; f < 4; ++f) {
    const float bt = b_t[f * 16 + l15];
    t[f] = (f32x4){bt, bt, bt, bt};
    const short8 b0 = *(const short8*)&Wt[(f * 16 + l15) * 72 + q * 8];
    const short8 b1 = *(const short8*)&Wt[(f * 16 + l15) * 72 + 32 + q * 8];
    t[f] = MFMA16(aZ0, b0, t[f]);
    t[f] = MFMA16(aZ1, b1, t[f]);
  }

  // ---- store t (bf16, [n][b][c]) + per-channel stats ----
  unsigned short* tp = (unsigned short*)(tg + (size_t)n * 4096);
#pragma unroll
  for (int f = 0; f < 4; ++f) {
    float s = 0.f, ss = 0.f;
#pragma unroll
    for (int j = 0; j < 4; ++j) {
      const float v = t[f][j];
      s += v; ss = fmaf(v, v, ss);
      tp[(r0 + q * 4 + j) * 64 + f * 16 + l15] = f2bf(v);
    }
    s  += __shfl_xor(s, 16);  s  += __shfl_xor(s, 32);
    ss += __shfl_xor(ss, 16); ss += __shfl_xor(ss, 32);
    if (lane < 16) {
      scr[w * 64 + f * 16 + l15]       = s;    // reuse colsum area (dead)
      scr[256 + w * 64 + f * 16 + l15] = ss;
    }
  }
  __syncthreads();  // S7
  if (tid < 64) {
    const float s  = scr[tid] + scr[64 + tid] + scr[128 + tid] + scr[192 + tid];
    const float ss = scr[256 + tid] + scr[320 + tid] + scr[384 + tid] + scr[448 + tid];
    float* st = stats + (n & 7) * 128;   // 8 copies to spread atomic contention
    atomicAdd(&st[tid], s);
    atomicAdd(&st[64 + tid], ss);
  }
}

// ---- k2: finalize BN stats ----------------------------------------------
__global__ void k2_stats(const float* __restrict__ stats, float* __restrict__ meanr) {
  const int c = threadIdx.x;
  if (c < 64) {
    float s = 0.f, ss = 0.f;
    for (int r = 0; r < 8; ++r) { s += stats[r * 128 + c]; ss += stats[r * 128 + 64 + c]; }
    const float inv = 1.0f / (float)(B_ * N_);
    const float mu = s * inv;
    const float var = fmaf(ss, inv, -mu * mu);
    meanr[c] = mu;
    meanr[64 + c] = rsqrtf(var + 1e-5f);
  }
}

// ---- k3: recompute X, BN+ReLU+residual, partial max over n ---------------
__global__ __launch_bounds__(256)
void k3_max(const float* __restrict__ x, const float* __restrict__ W_l,
            const float* __restrict__ b_l, const float* __restrict__ gamma,
            const float* __restrict__ beta, const __hip_bfloat16* __restrict__ tg,
            const float* __restrict__ meanr, float* __restrict__ pmax)
{
  const int b = blockIdx.x >> 3;      // 0..63
  const int chunk = blockIdx.x & 7;   // 0..7 (1024 n's each)
  const int c = threadIdx.x & 63;
  const int sub = threadIdx.x >> 6;   // 0..3
  float wl[10];
#pragma unroll
  for (int k = 0; k < 10; ++k) wl[k] = W_l[k * 64 + c];
  const float bl = b_l[c];
  const float g = gamma[c], be = beta[c];
  const float mu = meanr[c], rs = meanr[64 + c];
  float m = -1e30f;
  const int nbase = chunk * 1024 + sub;
  for (int j = 0; j < 256; ++j) {
    const int n = nbase + j * 4;
    const float* xp = x + ((size_t)b * N_ + n) * 10;
    float X = bl;
#pragma unroll
    for (int k = 0; k < 10; ++k) X = fmaf(xp[k], wl[k], X);
    const float t = __bfloat162float(tg[(size_t)n * 4096 + b * 64 + c]);
    const float tn = fmaf(g * (t - mu), rs, be);
    m = fmaxf(m, X + fmaxf(tn, 0.f));
  }
  __shared__ float sm[4][64];
  sm[sub][c] = m;
  __syncthreads();
  if (threadIdx.x < 64) {
    const float r = fmaxf(fmaxf(sm[0][c], sm[1][c]), fmaxf(sm[2][c], sm[3][c]));
    pmax[(size_t)blockIdx.x * 64 + c] = r;
  }
}

// ---- k4: final max over chunks -------------------------------------------
__global__ void k4_final(const float* __restrict__ pmax, float* __restrict__ out) {
  const int b = blockIdx.x, c = threadIdx.x;
  float m = -1e30f;
  for (int ch = 0; ch < 8; ++ch) m = fmaxf(m, pmax[((size_t)b * 8 + ch) * 64 + c]);
  out[b * 64 + c] = m;
}

// ---- launcher -------------------------------------------------------------
extern "C" void kernel_launch(void* const* d_in, const int* in_sizes, int n_in,
                              void* d_out, int out_size, void* d_ws, size_t ws_size,
                              hipStream_t stream) {
  const float* x     = (const float*)d_in[0];
  const float* y     = (const float*)d_in[1];
  const float* W_l   = (const float*)d_in[2];
  const float* b_l   = (const float*)d_in[3];
  const float* W_r   = (const float*)d_in[4];
  const float* b_r   = (const float*)d_in[5];
  const float* W_qk  = (const float*)d_in[6];
  const float* W_v   = (const float*)d_in[7];
  const float* b_v   = (const float*)d_in[8];
  const float* W_t   = (const float*)d_in[9];
  const float* b_t   = (const float*)d_in[10];
  const float* gamma = (const float*)d_in[11];
  const float* beta  = (const float*)d_in[12];
  float* out = (float*)d_out;

  char* ws = (char*)d_ws;
  __hip_bfloat16* tg = (__hip_bfloat16*)ws;                  // [N][B][C] bf16, 64 MB
  float* stats = (float*)(ws + (size_t)N_ * B_ * C_ * 2);    // 8 copies x 128
  float* meanr = stats + 1024;                               // mean[64] + rsig[64]
  float* pmax  = meanr + 128;                                // [512][64]

  hipLaunchKernelGGL(k0_init, dim3(4), dim3(256), 0, stream, stats);
  hipLaunchKernelGGL(k1_attn, dim3(N_), dim3(256), 0, stream,
                     x, y, W_l, b_l, W_r, b_r, W_qk, W_v, b_v, W_t, b_t, tg, stats);
  hipLaunchKernelGGL(k2_stats, dim3(1), dim3(64), 0, stream, stats, meanr);
  hipLaunchKernelGGL(k3_max, dim3(512), dim3(256), 0, stream,
                     x, W_l, b_l, gamma, beta, tg, meanr, pmax);
  hipLaunchKernelGGL(k4_final, dim3(64), dim3(64), 0, stream, pmax, out);
}